// Round 1
// 7290.474 us; speedup vs baseline: 1.2114x; 1.2114x over previous
//
#include <hip/hip_runtime.h>
#include <math.h>

namespace {

constexpr int kB  = 8192;
constexpr int kL  = 32;
constexpr int kV  = 256;
constexpr int kH  = 512;
constexpr int kE  = 256;
constexpr int kH3 = 1536;

__device__ __forceinline__ float sigm(float x) { return 1.0f / (1.0f + expf(-x)); }

__device__ __forceinline__ void gld_lds16(const float* g, float* lds) {
    __builtin_amdgcn_global_load_lds((const __attribute__((address_space(1))) void*)g,
                                     (__attribute__((address_space(3))) void*)lds, 16, 0, 0);
}
__device__ __forceinline__ void gld_lds4(const float* g, float* lds) {
    __builtin_amdgcn_global_load_lds((const __attribute__((address_space(1))) void*)g,
                                     (__attribute__((address_space(3))) void*)lds, 4, 0, 0);
}

// ---------------------------------------------------------------------------
// Generic 32x32 tiled transpose: out[C][R] = in[R][C]^T  (one-time)
// ---------------------------------------------------------------------------
__global__ __launch_bounds__(256) void transpose_kernel(
    const float* __restrict__ in, float* __restrict__ out, int R, int C)
{
    __shared__ float tile[32][33];
    const int tx = threadIdx.x & 31, ty = threadIdx.x >> 5;
    const int c0 = blockIdx.x * 32, r0 = blockIdx.y * 32;
#pragma unroll
    for (int i = 0; i < 4; ++i)
        tile[ty + i * 8][tx] = in[(size_t)(r0 + ty + i * 8) * C + c0 + tx];
    __syncthreads();
#pragma unroll
    for (int i = 0; i < 4; ++i)
        out[(size_t)(c0 + ty + i * 8) * R + r0 + tx] = tile[tx][ty + i * 8];
}

// ---------------------------------------------------------------------------
// G[257][1536] = [emb; sos] @ W_ih^T + b_ih   (one-time table; row 256 = SOS)
// ---------------------------------------------------------------------------
__global__ __launch_bounds__(256) void g_table_kernel(
    const float* __restrict__ emb, const float* __restrict__ sos,
    const float* __restrict__ W, const float* __restrict__ bias,
    float* __restrict__ G)
{
    __shared__ __align__(16) float As[32][64];
    __shared__ __align__(16) float Bs[32][64];
    const int tid = threadIdx.x;
    const int tn = tid & 15, tm = tid >> 4;
    const int m0 = blockIdx.x * 64;
    const int n0 = blockIdx.y * 64;
    float acc[4][4] = {};
    for (int kt = 0; kt < 8; ++kt) {
        const int k0 = kt * 32;
#pragma unroll
        for (int i = 0; i < 2; ++i) {
            int l = tid + i * 256;
            int r = l >> 3, kq = l & 7;
            int row = m0 + r;
            float4 v = make_float4(0.f, 0.f, 0.f, 0.f);
            if (row < 256)       v = *(const float4*)(emb + (size_t)row * kE + k0 + kq * 4);
            else if (row == 256) v = *(const float4*)(sos + k0 + kq * 4);
            As[kq*4+0][r] = v.x; As[kq*4+1][r] = v.y; As[kq*4+2][r] = v.z; As[kq*4+3][r] = v.w;
        }
#pragma unroll
        for (int i = 0; i < 2; ++i) {
            int l = tid + i * 256;
            int r = l >> 3, kq = l & 7;
            float4 v = *(const float4*)(W + (size_t)(n0 + r) * kE + k0 + kq * 4);
            Bs[kq*4+0][r] = v.x; Bs[kq*4+1][r] = v.y; Bs[kq*4+2][r] = v.z; Bs[kq*4+3][r] = v.w;
        }
        __syncthreads();
#pragma unroll
        for (int kk = 0; kk < 32; ++kk) {
            const float4 a = *(const float4*)(&As[kk][tm*4]);
            const float4 b = *(const float4*)(&Bs[kk][tn*4]);
            const float av[4] = {a.x, a.y, a.z, a.w};
            const float bv[4] = {b.x, b.y, b.z, b.w};
#pragma unroll
            for (int i = 0; i < 4; ++i)
#pragma unroll
                for (int j = 0; j < 4; ++j)
                    acc[i][j] = fmaf(av[i], bv[j], acc[i][j]);
        }
        __syncthreads();
    }
    const int cb = n0 + tn * 4;
    const float4 bb = *(const float4*)(bias + cb);
    const float bv[4] = {bb.x, bb.y, bb.z, bb.w};
#pragma unroll
    for (int i = 0; i < 4; ++i) {
        int row = m0 + tm * 4 + i;
        if (row < 257) {
            float4 o = make_float4(acc[i][0] + bv[0], acc[i][1] + bv[1],
                                   acc[i][2] + bv[2], acc[i][3] + bv[3]);
            *(float4*)(G + (size_t)row * kH3 + cb) = o;
        }
    }
}

// ---------------------------------------------------------------------------
// hT[512][8192] = (x @ W_i2h^T + b_i2h)^T    (one-time, writes transposed)
// ---------------------------------------------------------------------------
__global__ __launch_bounds__(256) void h0_kernel(
    const float* __restrict__ x, const float* __restrict__ W,
    const float* __restrict__ bias, float* __restrict__ hT)
{
    __shared__ __align__(16) float As[32][64];
    __shared__ __align__(16) float Bs[32][64];
    const int tid = threadIdx.x;
    const int tn = tid & 15, tm = tid >> 4;
    const int m0 = blockIdx.x * 64;   // batch
    const int n0 = blockIdx.y * 64;   // hidden j
    float acc[4][4] = {};
    for (int kt = 0; kt < 8; ++kt) {
        const int k0 = kt * 32;
#pragma unroll
        for (int i = 0; i < 2; ++i) {
            int l = tid + i * 256;
            int r = l >> 3, kq = l & 7;
            float4 v = *(const float4*)(x + (size_t)(m0 + r) * kE + k0 + kq * 4);
            As[kq*4+0][r] = v.x; As[kq*4+1][r] = v.y; As[kq*4+2][r] = v.z; As[kq*4+3][r] = v.w;
        }
#pragma unroll
        for (int i = 0; i < 2; ++i) {
            int l = tid + i * 256;
            int r = l >> 3, kq = l & 7;
            float4 v = *(const float4*)(W + (size_t)(n0 + r) * kE + k0 + kq * 4);
            Bs[kq*4+0][r] = v.x; Bs[kq*4+1][r] = v.y; Bs[kq*4+2][r] = v.z; Bs[kq*4+3][r] = v.w;
        }
        __syncthreads();
#pragma unroll
        for (int kk = 0; kk < 32; ++kk) {
            const float4 a = *(const float4*)(&As[kk][tm*4]);
            const float4 b = *(const float4*)(&Bs[kk][tn*4]);
            const float av[4] = {a.x, a.y, a.z, a.w};
            const float bv[4] = {b.x, b.y, b.z, b.w};
#pragma unroll
            for (int i = 0; i < 4; ++i)
#pragma unroll
                for (int j = 0; j < 4; ++j)
                    acc[i][j] = fmaf(av[i], bv[j], acc[i][j]);
        }
        __syncthreads();
    }
    const int cb = n0 + tn * 4;
    const float4 bb = *(const float4*)(bias + cb);
    const float bv[4] = {bb.x, bb.y, bb.z, bb.w};
#pragma unroll
    for (int i = 0; i < 4; ++i) {
        int row = m0 + tm * 4 + i;   // batch index
#pragma unroll
        for (int c = 0; c < 4; ++c)
            hT[(size_t)(cb + c) * kB + row] = acc[i][c] + bv[c];
    }
}

// ---------------------------------------------------------------------------
// GRU step: tile 128b x (32j x 3 gates). hT layout [k][b]. W_hhT [512][1536].
// Double-buffered LDS + raw s_barrier + counted vmcnt (T3/T4 2-phase):
// prefetch of tile kt+1 stays in flight across the barrier; only tile kt's
// 7 loads are waited (vmcnt(7)). 56 KB LDS -> 2 blocks/CU, 8 waves/CU.
// Thread: 8b x 2j x 3g = 48 acc.
// ---------------------------------------------------------------------------
__global__ __launch_bounds__(256, 2) void gru_step_kernel(
    const float* __restrict__ hT_in, const float* __restrict__ W_hhT,
    const float* __restrict__ b_hh, const float* __restrict__ G,
    const int* __restrict__ tok, const int t, float* __restrict__ hT_out)
{
    __shared__ __align__(16) float As[2][32 * 128];   // 2 x 16 KB  [k][b]
    __shared__ __align__(16) float Bs[2][32 * 96];    // 2 x 12 KB  [k][3g*32j]
    const int tid = threadIdx.x;
    const int tn = tid & 15;        // -> j pair
    const int tm = tid >> 4;        // -> 8 b's
    const int b0 = blockIdx.x * 128;
    const int j0 = blockIdx.y * 32;

    float acc[8][3][2] = {};

    // ---- stage tile kt into LDS buffer `buf` (async, lane-linear): 7 loads ----
    auto stage = [&](int kt, int buf) {
        const int k0 = kt * 32;
        float* as = As[buf];
        float* bs = Bs[buf];
#pragma unroll
        for (int i = 0; i < 4; ++i) {           // As: 32k x 128b
            int l = tid + i * 256;
            int r = l >> 5, c = l & 31;
            gld_lds16(hT_in + (size_t)(k0 + r) * kB + b0 + c * 4, &as[4 * l]);
        }
#pragma unroll
        for (int i = 0; i < 3; ++i) {           // Bs: 32k x 96n
            int l = tid + i * 256;
            int r = l / 24, q = l % 24;
            int g = q >> 3, cc = q & 7;
            gld_lds16(W_hhT + (size_t)(k0 + r) * kH3 + g * kH + j0 + cc * 4, &bs[4 * l]);
        }
    };

    stage(0, 0);
#pragma unroll 1
    for (int kt = 0; kt < 16; ++kt) {
        if (kt < 15) {
            stage(kt + 1, (kt + 1) & 1);                  // next tile in flight
            asm volatile("s_waitcnt vmcnt(7)" ::: "memory");  // only tile kt done
        } else {
            asm volatile("s_waitcnt vmcnt(0)" ::: "memory");
        }
        __builtin_amdgcn_s_barrier();
        __builtin_amdgcn_sched_barrier(0);
        const float* __restrict__ as = As[kt & 1];
        const float* __restrict__ bs = Bs[kt & 1];
#pragma unroll 8
        for (int kk = 0; kk < 32; ++kk) {
            const float4 a0 = *(const float4*)&as[kk * 128 + tm * 8];
            const float4 a1 = *(const float4*)&as[kk * 128 + tm * 8 + 4];
            const float2 br = *(const float2*)&bs[kk * 96 + tn * 2];
            const float2 bz = *(const float2*)&bs[kk * 96 + 32 + tn * 2];
            const float2 bn = *(const float2*)&bs[kk * 96 + 64 + tn * 2];
            const float av[8] = {a0.x, a0.y, a0.z, a0.w, a1.x, a1.y, a1.z, a1.w};
#pragma unroll
            for (int i = 0; i < 8; ++i) {
                acc[i][0][0] = fmaf(av[i], br.x, acc[i][0][0]);
                acc[i][0][1] = fmaf(av[i], br.y, acc[i][0][1]);
                acc[i][1][0] = fmaf(av[i], bz.x, acc[i][1][0]);
                acc[i][1][1] = fmaf(av[i], bz.y, acc[i][1][1]);
                acc[i][2][0] = fmaf(av[i], bn.x, acc[i][2][0]);
                acc[i][2][1] = fmaf(av[i], bn.y, acc[i][2][1]);
            }
        }
        __builtin_amdgcn_sched_barrier(0);
        __builtin_amdgcn_s_barrier();      // all waves done reading buf[kt&1]
        __builtin_amdgcn_sched_barrier(0); // keep next stage() below this barrier
    }

    // ---- epilogue: gates ----
    const int j  = j0 + tn * 2;
    const int bb = b0 + tm * 8;
    const float2 bhr = *(const float2*)&b_hh[j];
    const float2 bhz = *(const float2*)&b_hh[kH + j];
    const float2 bhn = *(const float2*)&b_hh[2 * kH + j];
    const float4 hp0a = *(const float4*)&hT_in[(size_t)j * kB + bb];
    const float4 hp0b = *(const float4*)&hT_in[(size_t)j * kB + bb + 4];
    const float4 hp1a = *(const float4*)&hT_in[(size_t)(j + 1) * kB + bb];
    const float4 hp1b = *(const float4*)&hT_in[(size_t)(j + 1) * kB + bb + 4];
    const float hp[2][8] = {
        {hp0a.x, hp0a.y, hp0a.z, hp0a.w, hp0b.x, hp0b.y, hp0b.z, hp0b.w},
        {hp1a.x, hp1a.y, hp1a.z, hp1a.w, hp1b.x, hp1b.y, hp1b.z, hp1b.w}};
    int rows[8];
    if (t == 0) {
#pragma unroll
        for (int i = 0; i < 8; ++i) rows[i] = 256;
    } else {
        const int4 t0 = *(const int4*)&tok[bb];
        const int4 t1 = *(const int4*)&tok[bb + 4];
        rows[0] = t0.x; rows[1] = t0.y; rows[2] = t0.z; rows[3] = t0.w;
        rows[4] = t1.x; rows[5] = t1.y; rows[6] = t1.z; rows[7] = t1.w;
    }
    float ho[2][8];
#pragma unroll
    for (int i = 0; i < 8; ++i) {
        const float* Gr = G + (size_t)rows[i] * kH3;
        const float2 gr = *(const float2*)&Gr[j];
        const float2 gz = *(const float2*)&Gr[kH + j];
        const float2 gn = *(const float2*)&Gr[2 * kH + j];
        float r0 = sigm(gr.x + acc[i][0][0] + bhr.x);
        float z0 = sigm(gz.x + acc[i][1][0] + bhz.x);
        float n0 = tanhf(gn.x + r0 * (acc[i][2][0] + bhn.x));
        ho[0][i] = (1.0f - z0) * n0 + z0 * hp[0][i];
        float r1 = sigm(gr.y + acc[i][0][1] + bhr.y);
        float z1 = sigm(gz.y + acc[i][1][1] + bhz.y);
        float n1 = tanhf(gn.y + r1 * (acc[i][2][1] + bhn.y));
        ho[1][i] = (1.0f - z1) * n1 + z1 * hp[1][i];
    }
    *(float4*)&hT_out[(size_t)j * kB + bb]           = make_float4(ho[0][0], ho[0][1], ho[0][2], ho[0][3]);
    *(float4*)&hT_out[(size_t)j * kB + bb + 4]       = make_float4(ho[0][4], ho[0][5], ho[0][6], ho[0][7]);
    *(float4*)&hT_out[(size_t)(j + 1) * kB + bb]     = make_float4(ho[1][0], ho[1][1], ho[1][2], ho[1][3]);
    *(float4*)&hT_out[(size_t)(j + 1) * kB + bb + 4] = make_float4(ho[1][4], ho[1][5], ho[1][6], ho[1][7]);
}

// ---------------------------------------------------------------------------
// Logits + argmax for step t. Tile 32b x 256v, grid 256, 512 threads
// (8 waves/CU, 2/SIMD — was 4 waves/CU). Thread: 2b x 8v (v strided by 32,
// conflict-free broadcast LDS reads). Double-buffered LDS staging via
// global_load_lds + counted vmcnt(6) raw-barrier pipeline.
// Per-output accumulation order identical to previous version (bit-exact).
// ---------------------------------------------------------------------------
__global__ __launch_bounds__(512, 2) void logit_kernel(
    const float* __restrict__ hT, const float* __restrict__ W_outT,
    const float* __restrict__ b_out, int* __restrict__ tok,
    float* __restrict__ out_tok, float* __restrict__ out_logits, const int t)
{
    __shared__ __align__(16) float As[2][32 * 32];     // 2 x 4 KB  [k][b]
    __shared__ __align__(16) float Bs[2][32 * 256];    // 2 x 32 KB [k][v]
    const int tid = threadIdx.x;
    const int tn = tid & 31;        // -> 8 v's (v = tn + 32m)
    const int tm = tid >> 5;        // -> 2 b's (b = 2*tm + i)
    const int b0 = blockIdx.x * 32;
    float acc[2][8] = {};

    // 6 loads/thread: 4x16B (Bs) + 2x4B (As), lane-linear LDS dests
    auto stage = [&](int kt, int buf) {
        const int k0 = kt * 32;
        float* as = As[buf];
        float* bs = Bs[buf];
#pragma unroll
        for (int i = 0; i < 4; ++i) {           // Bs: 32k x 256v, 2048 float4
            int l = tid + i * 512;
            int r = l >> 6, c = l & 63;
            gld_lds16(W_outT + (size_t)(k0 + r) * kV + c * 4, &bs[4 * l]);
        }
#pragma unroll
        for (int i = 0; i < 2; ++i) {           // As: 32k x 32b, 1024 dwords
            int l = tid + i * 512;
            int r = l >> 5, c = l & 31;
            gld_lds4(hT + (size_t)(k0 + r) * kB + b0 + c, &as[l]);
        }
    };

    stage(0, 0);
#pragma unroll 1
    for (int kt = 0; kt < 16; ++kt) {
        if (kt < 15) {
            stage(kt + 1, (kt + 1) & 1);
            asm volatile("s_waitcnt vmcnt(6)" ::: "memory");
        } else {
            asm volatile("s_waitcnt vmcnt(0)" ::: "memory");
        }
        __builtin_amdgcn_s_barrier();
        __builtin_amdgcn_sched_barrier(0);
        const float* __restrict__ as = As[kt & 1];
        const float* __restrict__ bs = Bs[kt & 1];
#pragma unroll 8
        for (int kk = 0; kk < 32; ++kk) {
            const float2 a = *(const float2*)&as[kk * 32 + tm * 2];
#pragma unroll
            for (int m = 0; m < 8; ++m) {
                const float bv = bs[kk * 256 + tn + m * 32];
                acc[0][m] = fmaf(a.x, bv, acc[0][m]);
                acc[1][m] = fmaf(a.y, bv, acc[1][m]);
            }
        }
        __builtin_amdgcn_sched_barrier(0);
        __builtin_amdgcn_s_barrier();
        __builtin_amdgcn_sched_barrier(0);
    }

    float bo[8];
#pragma unroll
    for (int m = 0; m < 8; ++m) bo[m] = b_out[tn + m * 32];
#pragma unroll
    for (int i = 0; i < 2; ++i) {
        const int b = b0 + tm * 2 + i;
        float mx = -INFINITY; int mi = 0;
        float* lp = out_logits + ((size_t)b * kL + t) * kV;
#pragma unroll
        for (int m = 0; m < 8; ++m) {
            const int vi = tn + m * 32;
            const float v = acc[i][m] + bo[m];
            lp[vi] = v;
            if (v > mx) { mx = v; mi = vi; }   // vi ascending -> first-max kept
        }
        // reduce across the 32 lanes that share this b (same half-wave)
#pragma unroll
        for (int s = 16; s >= 1; s >>= 1) {
            float pm = __shfl_xor(mx, s, 64);
            int   pi = __shfl_xor(mi, s, 64);
            if (pm > mx || (pm == mx && pi < mi)) { mx = pm; mi = pi; }
        }
        if (tn == 0) {
            tok[b] = mi;
            out_tok[(size_t)b * kL + t] = (float)mi;
        }
    }
}

} // namespace

extern "C" void kernel_launch(void* const* d_in, const int* in_sizes, int n_in,
                              void* d_out, int out_size, void* d_ws, size_t ws_size,
                              hipStream_t stream) {
    const float* x      = (const float*)d_in[0];
    const float* emb    = (const float*)d_in[1];
    const float* sos    = (const float*)d_in[2];
    const float* W_i2h  = (const float*)d_in[3];
    const float* b_i2h  = (const float*)d_in[4];
    const float* W_ih   = (const float*)d_in[5];
    const float* W_hh   = (const float*)d_in[6];
    const float* b_ih   = (const float*)d_in[7];
    const float* b_hh   = (const float*)d_in[8];
    const float* W_out  = (const float*)d_in[9];
    const float* b_out  = (const float*)d_in[10];

    float* out        = (float*)d_out;
    float* out_tok    = out;                         // [B*L] tokens as float
    float* out_logits = out + (size_t)kB * kL;       // [B*L*V]

    float* hA     = (float*)d_ws;                    // hT ping [512][8192]
    float* hB     = hA + (size_t)kH * kB;            // hT pong
    float* G      = hB + (size_t)kH * kB;            // [257][1536]
    float* W_hhT  = G + (size_t)257 * kH3;           // [512][1536]
    float* W_outT = W_hhT + (size_t)kH * kH3;        // [512][256]
    int*   tok    = (int*)(W_outT + (size_t)kH * kV);

    // one-time prep (independent)
    transpose_kernel<<<dim3(kH / 32, kH3 / 32), 256, 0, stream>>>(W_hh, W_hhT, kH3, kH);
    transpose_kernel<<<dim3(kH / 32, kV / 32), 256, 0, stream>>>(W_out, W_outT, kV, kH);
    g_table_kernel<<<dim3(5, kH3 / 64), 256, 0, stream>>>(emb, sos, W_ih, b_ih, G);
    h0_kernel<<<dim3(kB / 64, kH / 64), 256, 0, stream>>>(x, W_i2h, b_i2h, hA);

    for (int t = 0; t < kL; ++t) {
        float* hin  = (t & 1) ? hB : hA;
        float* hout = (t & 1) ? hA : hB;
        gru_step_kernel<<<dim3(kB / 128, kH / 32), 256, 0, stream>>>(
            hin, W_hhT, b_hh, G, tok, t, hout);
        logit_kernel<<<dim3(kB / 32), 512, 0, stream>>>(
            hout, W_outT, b_out, tok, out_tok, out_logits, t);
    }
}

// Round 3
// 6994.102 us; speedup vs baseline: 1.2627x; 1.0424x over previous
//
#include <hip/hip_runtime.h>
#include <math.h>

namespace {

constexpr int kB  = 8192;
constexpr int kL  = 32;
constexpr int kV  = 256;
constexpr int kH  = 512;
constexpr int kE  = 256;
constexpr int kH3 = 1536;

__device__ __forceinline__ float sigm(float x) { return 1.0f / (1.0f + expf(-x)); }

__device__ __forceinline__ void gld_lds16(const float* g, float* lds) {
    __builtin_amdgcn_global_load_lds((const __attribute__((address_space(1))) void*)g,
                                     (__attribute__((address_space(3))) void*)lds, 16, 0, 0);
}
__device__ __forceinline__ void gld_lds4(const float* g, float* lds) {
    __builtin_amdgcn_global_load_lds((const __attribute__((address_space(1))) void*)g,
                                     (__attribute__((address_space(3))) void*)lds, 4, 0, 0);
}

// ---------------------------------------------------------------------------
// Generic 32x32 tiled transpose: out[C][R] = in[R][C]^T  (one-time)
// ---------------------------------------------------------------------------
__global__ __launch_bounds__(256) void transpose_kernel(
    const float* __restrict__ in, float* __restrict__ out, int R, int C)
{
    __shared__ float tile[32][33];
    const int tx = threadIdx.x & 31, ty = threadIdx.x >> 5;
    const int c0 = blockIdx.x * 32, r0 = blockIdx.y * 32;
#pragma unroll
    for (int i = 0; i < 4; ++i)
        tile[ty + i * 8][tx] = in[(size_t)(r0 + ty + i * 8) * C + c0 + tx];
    __syncthreads();
#pragma unroll
    for (int i = 0; i < 4; ++i)
        out[(size_t)(c0 + ty + i * 8) * R + r0 + tx] = tile[tx][ty + i * 8];
}

// ---------------------------------------------------------------------------
// G[257][1536] = [emb; sos] @ W_ih^T + b_ih   (one-time table; row 256 = SOS)
// ---------------------------------------------------------------------------
__global__ __launch_bounds__(256) void g_table_kernel(
    const float* __restrict__ emb, const float* __restrict__ sos,
    const float* __restrict__ W, const float* __restrict__ bias,
    float* __restrict__ G)
{
    __shared__ __align__(16) float As[32][64];
    __shared__ __align__(16) float Bs[32][64];
    const int tid = threadIdx.x;
    const int tn = tid & 15, tm = tid >> 4;
    const int m0 = blockIdx.x * 64;
    const int n0 = blockIdx.y * 64;
    float acc[4][4] = {};
    for (int kt = 0; kt < 8; ++kt) {
        const int k0 = kt * 32;
#pragma unroll
        for (int i = 0; i < 2; ++i) {
            int l = tid + i * 256;
            int r = l >> 3, kq = l & 7;
            int row = m0 + r;
            float4 v = make_float4(0.f, 0.f, 0.f, 0.f);
            if (row < 256)       v = *(const float4*)(emb + (size_t)row * kE + k0 + kq * 4);
            else if (row == 256) v = *(const float4*)(sos + k0 + kq * 4);
            As[kq*4+0][r] = v.x; As[kq*4+1][r] = v.y; As[kq*4+2][r] = v.z; As[kq*4+3][r] = v.w;
        }
#pragma unroll
        for (int i = 0; i < 2; ++i) {
            int l = tid + i * 256;
            int r = l >> 3, kq = l & 7;
            float4 v = *(const float4*)(W + (size_t)(n0 + r) * kE + k0 + kq * 4);
            Bs[kq*4+0][r] = v.x; Bs[kq*4+1][r] = v.y; Bs[kq*4+2][r] = v.z; Bs[kq*4+3][r] = v.w;
        }
        __syncthreads();
#pragma unroll
        for (int kk = 0; kk < 32; ++kk) {
            const float4 a = *(const float4*)(&As[kk][tm*4]);
            const float4 b = *(const float4*)(&Bs[kk][tn*4]);
            const float av[4] = {a.x, a.y, a.z, a.w};
            const float bv[4] = {b.x, b.y, b.z, b.w};
#pragma unroll
            for (int i = 0; i < 4; ++i)
#pragma unroll
                for (int j = 0; j < 4; ++j)
                    acc[i][j] = fmaf(av[i], bv[j], acc[i][j]);
        }
        __syncthreads();
    }
    const int cb = n0 + tn * 4;
    const float4 bb = *(const float4*)(bias + cb);
    const float bv[4] = {bb.x, bb.y, bb.z, bb.w};
#pragma unroll
    for (int i = 0; i < 4; ++i) {
        int row = m0 + tm * 4 + i;
        if (row < 257) {
            float4 o = make_float4(acc[i][0] + bv[0], acc[i][1] + bv[1],
                                   acc[i][2] + bv[2], acc[i][3] + bv[3]);
            *(float4*)(G + (size_t)row * kH3 + cb) = o;
        }
    }
}

// ---------------------------------------------------------------------------
// hT[512][8192] = (x @ W_i2h^T + b_i2h)^T    (one-time, writes transposed)
// ---------------------------------------------------------------------------
__global__ __launch_bounds__(256) void h0_kernel(
    const float* __restrict__ x, const float* __restrict__ W,
    const float* __restrict__ bias, float* __restrict__ hT)
{
    __shared__ __align__(16) float As[32][64];
    __shared__ __align__(16) float Bs[32][64];
    const int tid = threadIdx.x;
    const int tn = tid & 15, tm = tid >> 4;
    const int m0 = blockIdx.x * 64;   // batch
    const int n0 = blockIdx.y * 64;   // hidden j
    float acc[4][4] = {};
    for (int kt = 0; kt < 8; ++kt) {
        const int k0 = kt * 32;
#pragma unroll
        for (int i = 0; i < 2; ++i) {
            int l = tid + i * 256;
            int r = l >> 3, kq = l & 7;
            float4 v = *(const float4*)(x + (size_t)(m0 + r) * kE + k0 + kq * 4);
            As[kq*4+0][r] = v.x; As[kq*4+1][r] = v.y; As[kq*4+2][r] = v.z; As[kq*4+3][r] = v.w;
        }
#pragma unroll
        for (int i = 0; i < 2; ++i) {
            int l = tid + i * 256;
            int r = l >> 3, kq = l & 7;
            float4 v = *(const float4*)(W + (size_t)(n0 + r) * kE + k0 + kq * 4);
            Bs[kq*4+0][r] = v.x; Bs[kq*4+1][r] = v.y; Bs[kq*4+2][r] = v.z; Bs[kq*4+3][r] = v.w;
        }
        __syncthreads();
#pragma unroll
        for (int kk = 0; kk < 32; ++kk) {
            const float4 a = *(const float4*)(&As[kk][tm*4]);
            const float4 b = *(const float4*)(&Bs[kk][tn*4]);
            const float av[4] = {a.x, a.y, a.z, a.w};
            const float bv[4] = {b.x, b.y, b.z, b.w};
#pragma unroll
            for (int i = 0; i < 4; ++i)
#pragma unroll
                for (int j = 0; j < 4; ++j)
                    acc[i][j] = fmaf(av[i], bv[j], acc[i][j]);
        }
        __syncthreads();
    }
    const int cb = n0 + tn * 4;
    const float4 bb = *(const float4*)(bias + cb);
    const float bv[4] = {bb.x, bb.y, bb.z, bb.w};
#pragma unroll
    for (int i = 0; i < 4; ++i) {
        int row = m0 + tm * 4 + i;   // batch index
#pragma unroll
        for (int c = 0; c < 4; ++c)
            hT[(size_t)(cb + c) * kB + row] = acc[i][c] + bv[c];
    }
}

// ---------------------------------------------------------------------------
// GRU step: tile 128b x (64j x 3 gates), K-tile 16, double-buffered (40 KB).
// hT layout [k][b]. W_hhT [512][1536]. Counted-vmcnt 2-phase pipeline.
// Thread: 8b x 4j x 3g = 96 acc; 5 ds_read_b128 per kk -> 96 FMA
// (was 5 reads -> 48 FMA): halves LDS-pipe load per FMA.
// Per-output k-accumulation order unchanged (ascending k) -> bit-exact.
// ---------------------------------------------------------------------------
__global__ __launch_bounds__(256, 2) void gru_step_kernel(
    const float* __restrict__ hT_in, const float* __restrict__ W_hhT,
    const float* __restrict__ b_hh, const float* __restrict__ G,
    const int* __restrict__ tok, const int t, float* __restrict__ hT_out)
{
    __shared__ __align__(16) float As[2][16 * 128];   // 2 x 8 KB   [k][b]
    __shared__ __align__(16) float Bs[2][16 * 192];   // 2 x 12 KB  [k][3g*64j]
    const int tid = threadIdx.x;
    const int tn = tid & 15;        // -> j quad (j = j0 + tn*4)
    const int tm = tid >> 4;        // -> 8 b's  (b = b0 + tm*8)
    const int b0 = blockIdx.x * 128;
    const int j0 = blockIdx.y * 64;

    float acc[8][3][4] = {};

    // ---- stage K-tile kt into LDS buffer `buf` (async, lane-linear): 5 loads
    auto stage = [&](int kt, int buf) {
        const int k0 = kt * 16;
        float* as = As[buf];
        float* bs = Bs[buf];
#pragma unroll
        for (int i = 0; i < 2; ++i) {           // As: 16k x 128b = 512 float4
            int l = tid + i * 256;
            int r = l >> 5, c = l & 31;
            gld_lds16(hT_in + (size_t)(k0 + r) * kB + b0 + c * 4, &as[4 * l]);
        }
#pragma unroll
        for (int i = 0; i < 3; ++i) {           // Bs: 16k x 192 = 768 float4
            int l = tid + i * 256;
            int r = l / 48, q = l % 48;         // row, col-quad
            int g = q >> 4, cc = q & 15;        // gate, j-quad within gate
            gld_lds16(W_hhT + (size_t)(k0 + r) * kH3 + g * kH + j0 + cc * 4, &bs[4 * l]);
        }
    };

    stage(0, 0);
#pragma unroll 1
    for (int kt = 0; kt < 32; ++kt) {
        if (kt < 31) {
            stage(kt + 1, (kt + 1) & 1);                  // next tile in flight
            asm volatile("s_waitcnt vmcnt(5)" ::: "memory");  // only tile kt done
        } else {
            asm volatile("s_waitcnt vmcnt(0)" ::: "memory");
        }
        __builtin_amdgcn_s_barrier();
        __builtin_amdgcn_sched_barrier(0);
        const float* __restrict__ as = As[kt & 1];
        const float* __restrict__ bs = Bs[kt & 1];
#pragma unroll
        for (int kk = 0; kk < 16; ++kk) {
            const float4 a0 = *(const float4*)&as[kk * 128 + tm * 8];
            const float4 a1 = *(const float4*)&as[kk * 128 + tm * 8 + 4];
            const float4 br = *(const float4*)&bs[kk * 192 + tn * 4];
            const float4 bz = *(const float4*)&bs[kk * 192 + 64 + tn * 4];
            const float4 bn = *(const float4*)&bs[kk * 192 + 128 + tn * 4];
            const float av[8]  = {a0.x, a0.y, a0.z, a0.w, a1.x, a1.y, a1.z, a1.w};
            const float brv[4] = {br.x, br.y, br.z, br.w};
            const float bzv[4] = {bz.x, bz.y, bz.z, bz.w};
            const float bnv[4] = {bn.x, bn.y, bn.z, bn.w};
#pragma unroll
            for (int i = 0; i < 8; ++i)
#pragma unroll
                for (int jj = 0; jj < 4; ++jj) {
                    acc[i][0][jj] = fmaf(av[i], brv[jj], acc[i][0][jj]);
                    acc[i][1][jj] = fmaf(av[i], bzv[jj], acc[i][1][jj]);
                    acc[i][2][jj] = fmaf(av[i], bnv[jj], acc[i][2][jj]);
                }
        }
        __builtin_amdgcn_sched_barrier(0);
        __builtin_amdgcn_s_barrier();      // all waves done reading buf[kt&1]
        __builtin_amdgcn_sched_barrier(0); // keep next stage() below this barrier
    }

    // ---- epilogue: gates ----
    const int j  = j0 + tn * 4;
    const int bb = b0 + tm * 8;
    const float4 bhr = *(const float4*)&b_hh[j];
    const float4 bhz = *(const float4*)&b_hh[kH + j];
    const float4 bhn = *(const float4*)&b_hh[2 * kH + j];
    const float bhrv[4] = {bhr.x, bhr.y, bhr.z, bhr.w};
    const float bhzv[4] = {bhz.x, bhz.y, bhz.z, bhz.w};
    const float bhnv[4] = {bhn.x, bhn.y, bhn.z, bhn.w};

    float hp[4][8];
#pragma unroll
    for (int jj = 0; jj < 4; ++jj) {
        const float4 p0 = *(const float4*)&hT_in[(size_t)(j + jj) * kB + bb];
        const float4 p1 = *(const float4*)&hT_in[(size_t)(j + jj) * kB + bb + 4];
        hp[jj][0] = p0.x; hp[jj][1] = p0.y; hp[jj][2] = p0.z; hp[jj][3] = p0.w;
        hp[jj][4] = p1.x; hp[jj][5] = p1.y; hp[jj][6] = p1.z; hp[jj][7] = p1.w;
    }

    int rows[8];
    if (t == 0) {
#pragma unroll
        for (int i = 0; i < 8; ++i) rows[i] = 256;
    } else {
        const int4 t0 = *(const int4*)&tok[bb];
        const int4 t1 = *(const int4*)&tok[bb + 4];
        rows[0] = t0.x; rows[1] = t0.y; rows[2] = t0.z; rows[3] = t0.w;
        rows[4] = t1.x; rows[5] = t1.y; rows[6] = t1.z; rows[7] = t1.w;
    }

    float ho[4][8];
#pragma unroll
    for (int i = 0; i < 8; ++i) {
        const float* Gr = G + (size_t)rows[i] * kH3;
        const float4 gr = *(const float4*)&Gr[j];
        const float4 gz = *(const float4*)&Gr[kH + j];
        const float4 gn = *(const float4*)&Gr[2 * kH + j];
        const float grv[4] = {gr.x, gr.y, gr.z, gr.w};
        const float gzv[4] = {gz.x, gz.y, gz.z, gz.w};
        const float gnv[4] = {gn.x, gn.y, gn.z, gn.w};
#pragma unroll
        for (int jj = 0; jj < 4; ++jj) {
            float r = sigm(grv[jj] + acc[i][0][jj] + bhrv[jj]);
            float z = sigm(gzv[jj] + acc[i][1][jj] + bhzv[jj]);
            float n = tanhf(gnv[jj] + r * (acc[i][2][jj] + bhnv[jj]));
            ho[jj][i] = (1.0f - z) * n + z * hp[jj][i];
        }
    }
#pragma unroll
    for (int jj = 0; jj < 4; ++jj) {
        *(float4*)&hT_out[(size_t)(j + jj) * kB + bb]     =
            make_float4(ho[jj][0], ho[jj][1], ho[jj][2], ho[jj][3]);
        *(float4*)&hT_out[(size_t)(j + jj) * kB + bb + 4] =
            make_float4(ho[jj][4], ho[jj][5], ho[jj][6], ho[jj][7]);
    }
}

// ---------------------------------------------------------------------------
// Logits + argmax for step t. Tile 32b x 256v, grid 256, 512 threads
// (8 waves/CU, 2/SIMD). Thread: 2b x 8v (v strided by 32, conflict-free
// broadcast LDS reads). Double-buffered LDS staging via global_load_lds +
// counted vmcnt(6) raw-barrier pipeline.
// ---------------------------------------------------------------------------
__global__ __launch_bounds__(512, 2) void logit_kernel(
    const float* __restrict__ hT, const float* __restrict__ W_outT,
    const float* __restrict__ b_out, int* __restrict__ tok,
    float* __restrict__ out_tok, float* __restrict__ out_logits, const int t)
{
    __shared__ __align__(16) float As[2][32 * 32];     // 2 x 4 KB  [k][b]
    __shared__ __align__(16) float Bs[2][32 * 256];    // 2 x 32 KB [k][v]
    const int tid = threadIdx.x;
    const int tn = tid & 31;        // -> 8 v's (v = tn + 32m)
    const int tm = tid >> 5;        // -> 2 b's (b = 2*tm + i)
    const int b0 = blockIdx.x * 32;
    float acc[2][8] = {};

    // 6 loads/thread: 4x16B (Bs) + 2x4B (As), lane-linear LDS dests
    auto stage = [&](int kt, int buf) {
        const int k0 = kt * 32;
        float* as = As[buf];
        float* bs = Bs[buf];
#pragma unroll
        for (int i = 0; i < 4; ++i) {           // Bs: 32k x 256v, 2048 float4
            int l = tid + i * 512;
            int r = l >> 6, c = l & 63;
            gld_lds16(W_outT + (size_t)(k0 + r) * kV + c * 4, &bs[4 * l]);
        }
#pragma unroll
        for (int i = 0; i < 2; ++i) {           // As: 32k x 32b, 1024 dwords
            int l = tid + i * 512;
            int r = l >> 5, c = l & 31;
            gld_lds4(hT + (size_t)(k0 + r) * kB + b0 + c, &as[l]);
        }
    };

    stage(0, 0);
#pragma unroll 1
    for (int kt = 0; kt < 16; ++kt) {
        if (kt < 15) {
            stage(kt + 1, (kt + 1) & 1);
            asm volatile("s_waitcnt vmcnt(6)" ::: "memory");
        } else {
            asm volatile("s_waitcnt vmcnt(0)" ::: "memory");
        }
        __builtin_amdgcn_s_barrier();
        __builtin_amdgcn_sched_barrier(0);
        const float* __restrict__ as = As[kt & 1];
        const float* __restrict__ bs = Bs[kt & 1];
#pragma unroll 8
        for (int kk = 0; kk < 32; ++kk) {
            const float2 a = *(const float2*)&as[kk * 32 + tm * 2];
#pragma unroll
            for (int m = 0; m < 8; ++m) {
                const float bv = bs[kk * 256 + tn + m * 32];
                acc[0][m] = fmaf(a.x, bv, acc[0][m]);
                acc[1][m] = fmaf(a.y, bv, acc[1][m]);
            }
        }
        __builtin_amdgcn_sched_barrier(0);
        __builtin_amdgcn_s_barrier();
        __builtin_amdgcn_sched_barrier(0);
    }

    float bo[8];
#pragma unroll
    for (int m = 0; m < 8; ++m) bo[m] = b_out[tn + m * 32];
#pragma unroll
    for (int i = 0; i < 2; ++i) {
        const int b = b0 + tm * 2 + i;
        float mx = -INFINITY; int mi = 0;
        float* lp = out_logits + ((size_t)b * kL + t) * kV;
#pragma unroll
        for (int m = 0; m < 8; ++m) {
            const int vi = tn + m * 32;
            const float v = acc[i][m] + bo[m];
            lp[vi] = v;
            if (v > mx) { mx = v; mi = vi; }   // vi ascending -> first-max kept
        }
        // reduce across the 32 lanes that share this b (same half-wave)
#pragma unroll
        for (int s = 16; s >= 1; s >>= 1) {
            float pm = __shfl_xor(mx, s, 64);
            int   pi = __shfl_xor(mi, s, 64);
            if (pm > mx || (pm == mx && pi < mi)) { mx = pm; mi = pi; }
        }
        if (tn == 0) {
            tok[b] = mi;
            out_tok[(size_t)b * kL + t] = (float)mi;
        }
    }
}

} // namespace

extern "C" void kernel_launch(void* const* d_in, const int* in_sizes, int n_in,
                              void* d_out, int out_size, void* d_ws, size_t ws_size,
                              hipStream_t stream) {
    const float* x      = (const float*)d_in[0];
    const float* emb    = (const float*)d_in[1];
    const float* sos    = (const float*)d_in[2];
    const float* W_i2h  = (const float*)d_in[3];
    const float* b_i2h  = (const float*)d_in[4];
    const float* W_ih   = (const float*)d_in[5];
    const float* W_hh   = (const float*)d_in[6];
    const float* b_ih   = (const float*)d_in[7];
    const float* b_hh   = (const float*)d_in[8];
    const float* W_out  = (const float*)d_in[9];
    const float* b_out  = (const float*)d_in[10];

    float* out        = (float*)d_out;
    float* out_tok    = out;                         // [B*L] tokens as float
    float* out_logits = out + (size_t)kB * kL;       // [B*L*V]

    float* hA     = (float*)d_ws;                    // hT ping [512][8192]
    float* hB     = hA + (size_t)kH * kB;            // hT pong
    float* G      = hB + (size_t)kH * kB;            // [257][1536]
    float* W_hhT  = G + (size_t)257 * kH3;           // [512][1536]
    float* W_outT = W_hhT + (size_t)kH * kH3;        // [512][256]
    int*   tok    = (int*)(W_outT + (size_t)kH * kV);

    // one-time prep (independent)
    transpose_kernel<<<dim3(kH / 32, kH3 / 32), 256, 0, stream>>>(W_hh, W_hhT, kH3, kH);
    transpose_kernel<<<dim3(kH / 32, kV / 32), 256, 0, stream>>>(W_out, W_outT, kV, kH);
    g_table_kernel<<<dim3(5, kH3 / 64), 256, 0, stream>>>(emb, sos, W_ih, b_ih, G);
    h0_kernel<<<dim3(kB / 64, kH / 64), 256, 0, stream>>>(x, W_i2h, b_i2h, hA);

    for (int t = 0; t < kL; ++t) {
        float* hin  = (t & 1) ? hB : hA;
        float* hout = (t & 1) ? hA : hB;
        gru_step_kernel<<<dim3(kB / 128, kH / 64), 256, 0, stream>>>(
            hin, W_hhT, b_hh, G, tok, t, hout);
        logit_kernel<<<dim3(kB / 32), 512, 0, stream>>>(
            hout, W_outT, b_out, tok, out_tok, out_logits, t);
    }
}